// Round 5
// baseline (304.225 us; speedup 1.0000x reference)
//
#include <hip/hip_runtime.h>
#include <hip/hip_bf16.h>
#include <math.h>

// Problem constants
#define BB 256
#define KK 32
#define DD 128
#define HH 256
#define NN 16
// d_out layout (fp32, concatenated in return order)
#define O0 ((size_t)0)
#define O1 ((size_t)33554432)
#define O2 ((size_t)37748736)
#define O3 ((size_t)71303168)

typedef float f32x4 __attribute__((ext_vector_type(4)));
typedef short s16x8 __attribute__((ext_vector_type(8)));

static __device__ __forceinline__ short f2bf(float x) {
  __hip_bfloat16 h = __float2bfloat16(x);
  return *reinterpret_cast<short*>(&h);
}
static __device__ __forceinline__ float bf2f(short s) {
  __hip_bfloat16 h;
  *reinterpret_cast<short*>(&h) = s;
  return __bfloat162float(h);
}

// exact-erf gelu via Abramowitz-Stegun 7.1.26 (|erf err| <= 1.5e-7)
static __device__ __forceinline__ float gelu_exact(float x) {
  float ax = fabsf(x) * 0.70710678118654752f;
  float t = __builtin_amdgcn_rcpf(fmaf(0.3275911f, ax, 1.0f));
  float p = fmaf(1.061405429f, t, -1.453152027f);
  p = fmaf(p, t, 1.421413741f);
  p = fmaf(p, t, -0.284496736f);
  p = fmaf(p, t, 0.254829592f);
  p *= t;
  float e = __expf(-ax * ax);
  float er = fmaf(-p, e, 1.0f);  // erf(|x|/sqrt2)
  er = copysignf(er, x);
  return 0.5f * x * (1.0f + er);
}

// ---------------------------------------------------------------------------
// Prep: z -> bf16; W1 -> transposed hi/lo bf16 [col 512][k 128];
//       W2 -> transposed hi/lo bf16 [col 128][k 256]; cb -> hi/lo [n][k];
//       cbT -> bf16 [c 128][n 32] (n 16..31 zero-padded, for Phase M MFMA).
// ---------------------------------------------------------------------------
__global__ __launch_bounds__(256) void prep_kernel(
    const float* __restrict__ z, const float* __restrict__ W1,
    const float* __restrict__ W2, const float* __restrict__ cb,
    short* __restrict__ zb, short* __restrict__ W1th, short* __restrict__ W1tl,
    short* __restrict__ Wh, short* __restrict__ Wl,
    short* __restrict__ cbh, short* __restrict__ cbl, short* __restrict__ cbT) {
  const int idx = blockIdx.x * 256 + threadIdx.x;  // 1,048,576 total
  zb[idx] = f2bf(z[idx]);
  if (idx < 512 * 128) {  // W1t
    int c = idx >> 7, k = idx & 127;
    float w = (c < 256) ? W1[(size_t)k * 256 + c]
                        : W1[(size_t)(128 + k) * 256 + (c - 256)];
    short h = f2bf(w);
    W1th[idx] = h;
    W1tl[idx] = f2bf(w - bf2f(h));
  }
  if (idx < 128 * 256) {  // W2t: [c][k]
    int c = idx >> 8, k = idx & 255;
    float w = W2[(size_t)k * 128 + c];
    short h = f2bf(w);
    Wh[idx] = h;
    Wl[idx] = f2bf(w - bf2f(h));
  }
  if (idx < 2048) {  // cb [n][k] splits
    float v = cb[idx];
    short h = f2bf(v);
    cbh[idx] = h;
    cbl[idx] = f2bf(v - bf2f(h));
  }
  if (idx < 128 * 32) {  // cbT [c][n], zero-padded n>=16
    int c = idx >> 5, n = idx & 31;
    cbT[idx] = (n < 16) ? f2bf(cb[(size_t)n * 128 + c]) : (short)0;
  }
}

// ---------------------------------------------------------------------------
// H projection via MFMA: Hcat[8192][512] = zb(8192x128) @ W1t^T (split-bf16).
// ---------------------------------------------------------------------------
__global__ __launch_bounds__(256) void hproj_mfma(
    const short* __restrict__ zb, const short* __restrict__ W1th,
    const short* __restrict__ W1tl, float* __restrict__ H) {
  const int tid = threadIdx.x;
  const int lane = tid & 63;
  const int wv = tid >> 6;
  const int l4 = lane >> 4, l15 = lane & 15;
  const int row0 = blockIdx.x * 32;
  const int col0 = blockIdx.y * 128 + wv * 32;

  f32x4 acc[2][2];
#pragma unroll
  for (int mt = 0; mt < 2; ++mt)
#pragma unroll
    for (int nt = 0; nt < 2; ++nt)
      acc[mt][nt] = (f32x4){0.f, 0.f, 0.f, 0.f};

#pragma unroll
  for (int ks = 0; ks < 4; ++ks) {
    const int kof = ks * 32 + l4 * 8;
    s16x8 a0 = *(const s16x8*)(zb + (size_t)(row0 + l15) * 128 + kof);
    s16x8 a1 = *(const s16x8*)(zb + (size_t)(row0 + 16 + l15) * 128 + kof);
    s16x8 bh0 = *(const s16x8*)(W1th + (size_t)(col0 + l15) * 128 + kof);
    s16x8 bh1 = *(const s16x8*)(W1th + (size_t)(col0 + 16 + l15) * 128 + kof);
    s16x8 bl0 = *(const s16x8*)(W1tl + (size_t)(col0 + l15) * 128 + kof);
    s16x8 bl1 = *(const s16x8*)(W1tl + (size_t)(col0 + 16 + l15) * 128 + kof);
    acc[0][0] = __builtin_amdgcn_mfma_f32_16x16x32_bf16(a0, bh0, acc[0][0], 0, 0, 0);
    acc[0][0] = __builtin_amdgcn_mfma_f32_16x16x32_bf16(a0, bl0, acc[0][0], 0, 0, 0);
    acc[0][1] = __builtin_amdgcn_mfma_f32_16x16x32_bf16(a0, bh1, acc[0][1], 0, 0, 0);
    acc[0][1] = __builtin_amdgcn_mfma_f32_16x16x32_bf16(a0, bl1, acc[0][1], 0, 0, 0);
    acc[1][0] = __builtin_amdgcn_mfma_f32_16x16x32_bf16(a1, bh0, acc[1][0], 0, 0, 0);
    acc[1][0] = __builtin_amdgcn_mfma_f32_16x16x32_bf16(a1, bl0, acc[1][0], 0, 0, 0);
    acc[1][1] = __builtin_amdgcn_mfma_f32_16x16x32_bf16(a1, bh1, acc[1][1], 0, 0, 0);
    acc[1][1] = __builtin_amdgcn_mfma_f32_16x16x32_bf16(a1, bl1, acc[1][1], 0, 0, 0);
  }

#pragma unroll
  for (int mt = 0; mt < 2; ++mt)
#pragma unroll
    for (int nt = 0; nt < 2; ++nt)
#pragma unroll
      for (int r = 0; r < 4; ++r)
        H[(size_t)(row0 + mt * 16 + l4 * 4 + r) * 512 + col0 + nt * 16 + l15] =
            acc[mt][nt][r];
}

// ---------------------------------------------------------------------------
// Kernel B: one block (4 waves) per (b, i, j-half): 16 j's.
//  A: gelu(Hi+Hj+b1) -> split bf16 in swizzled LDS (16x256)
//  G: e = A @ W2 (3-pass split-bf16 MFMA; wave owns 32 cols, M=16)
//  E: e fp32 -> global from regs; bf16 splits -> swizzled LDS
//  L: logits = e @ cbT*10 (MFMA, wave 0), softmax in-register
//  M: m = alpha @ cb (one 16x16x32 MFMA per 16-col group, n zero-padded)
// ---------------------------------------------------------------------------
__global__ __launch_bounds__(256, 8) void pair_kernel(
    const float* __restrict__ Hcat, const float* __restrict__ b1,
    const short* __restrict__ Wh, const short* __restrict__ Wl,
    const float* __restrict__ b2, const short* __restrict__ cbh,
    const short* __restrict__ cbl, const short* __restrict__ cbT,
    float* __restrict__ out) {
  __shared__ short sAh[16 * 256];  // 8 KB gelu hi split, XOR-swizzled
  __shared__ union {
    short Al[16 * 256];  // 8 KB gelu lo split (dead after G)
    struct { short Eh[16 * 128]; short El[16 * 128]; } e;
  } u;
  __shared__ short sAlp[16 * 32];  // 1 KB alpha bf16, n zero-padded to 32

  const int tid = threadIdx.x;
  const int blk = blockIdx.x;      // = (b*K + i)*2 + jhalf
  const int bi = blk >> 1;         // b*K + i
  const int b = blk >> 6;
  const int j0 = (blk & 1) * 16;

  // zero-init alpha pad (k 16..31 stays 0)
  ((unsigned*)sAlp)[tid] = 0u;     // 256 u32 = 1 KB

  // ---- Phase A: gelu + split-bf16 into swizzled LDS (16 rows) ----
  {
    const int k0 = (tid & 127) * 2;
    const int pb = (tid >> 7) * 8;
    const float2 hiv = *(const float2*)(Hcat + (size_t)bi * 512 + k0);
    const float2 b1v = *(const float2*)(b1 + k0);
    const float hx = hiv.x + b1v.x;
    const float hy = hiv.y + b1v.y;
    const float* hjp = Hcat + ((size_t)b * KK + j0 + pb) * 512 + 256 + k0;
    unsigned* aH = (unsigned*)sAh;
    unsigned* aL = (unsigned*)u.Al;
    const int cw = tid & 127;
#pragma unroll 4
    for (int p = 0; p < 8; ++p) {
      const int row = pb + p;
      float2 hj = *(const float2*)(hjp + (size_t)p * 512);
      float g0 = gelu_exact(hx + hj.x);
      float g1 = gelu_exact(hy + hj.y);
      short h0 = f2bf(g0), h1 = f2bf(g1);
      short l0 = f2bf(g0 - bf2f(h0)), l1 = f2bf(g1 - bf2f(h1));
      const int wi = row * 128 + ((cw ^ ((row & 7) << 2)));
      aH[wi] = (unsigned)(unsigned short)h0 | ((unsigned)(unsigned short)h1 << 16);
      aL[wi] = (unsigned)(unsigned short)l0 | ((unsigned)(unsigned short)l1 << 16);
    }
  }
  __syncthreads();

  // ---- Phase G: 16x128 GEMM, K=256, split-bf16 MFMA ----
  const int lane = tid & 63;
  const int wv = tid >> 6;  // wave owns cols nb..nb+31
  const int nb = wv * 32;
  const int l4 = lane >> 4;
  const int l15 = lane & 15;

  f32x4 acc0 = (f32x4){0.f, 0.f, 0.f, 0.f};
  f32x4 acc1 = (f32x4){0.f, 0.f, 0.f, 0.f};

  const int sw = (l15 & 7) << 4;
  const char* pAh = (const char*)sAh;
  const char* pAl = (const char*)u.Al;
  const size_t gB0 = (size_t)(nb + l15) * 256 + l4 * 8;

#pragma unroll
  for (int ks = 0; ks < 8; ++ks) {
    const int cbyte = ks * 64 + l4 * 16;
    const int o0 = l15 * 512 + (cbyte ^ sw);
    s16x8 ah = *(const s16x8*)(pAh + o0);
    s16x8 al = *(const s16x8*)(pAl + o0);
    const size_t g0 = gB0 + ks * 32;
    const size_t g1 = g0 + 16 * 256;
    s16x8 bh0 = *(const s16x8*)(Wh + g0);
    s16x8 bh1 = *(const s16x8*)(Wh + g1);
    s16x8 bl0 = *(const s16x8*)(Wl + g0);
    s16x8 bl1 = *(const s16x8*)(Wl + g1);

    acc0 = __builtin_amdgcn_mfma_f32_16x16x32_bf16(ah, bh0, acc0, 0, 0, 0);
    acc0 = __builtin_amdgcn_mfma_f32_16x16x32_bf16(al, bh0, acc0, 0, 0, 0);
    acc0 = __builtin_amdgcn_mfma_f32_16x16x32_bf16(ah, bl0, acc0, 0, 0, 0);
    acc1 = __builtin_amdgcn_mfma_f32_16x16x32_bf16(ah, bh1, acc1, 0, 0, 0);
    acc1 = __builtin_amdgcn_mfma_f32_16x16x32_bf16(al, bh1, acc1, 0, 0, 0);
    acc1 = __builtin_amdgcn_mfma_f32_16x16x32_bf16(ah, bl1, acc1, 0, 0, 0);
  }

  __syncthreads();  // A-bufs fully consumed; u.e may be written

  // ---- Phase E: +b2, fp32 e to global from regs, bf16 splits to LDS ----
  {
    const float b2v0 = b2[nb + l15];
    const float b2v1 = b2[nb + 16 + l15];
    float* eg = out + O2 + ((size_t)bi * KK + j0) * DD;
    char* pEh = (char*)u.e.Eh;
    char* pEl = (char*)u.e.El;
#pragma unroll
    for (int r = 0; r < 4; ++r) {
      const int row = l4 * 4 + r;
      const int rsw = (row & 7) << 4;
      const float e0 = acc0[r] + b2v0;
      const float e1 = acc1[r] + b2v1;
      eg[row * 128 + nb + l15] = e0;
      eg[row * 128 + nb + 16 + l15] = e1;
      short h0 = f2bf(e0), h1 = f2bf(e1);
      short lo0 = f2bf(e0 - bf2f(h0)), lo1 = f2bf(e1 - bf2f(h1));
      const int i0 = row * 256 + (((nb + l15) * 2) ^ rsw);
      const int i1 = row * 256 + (((nb + 16 + l15) * 2) ^ rsw);
      *(short*)(pEh + i0) = h0;
      *(short*)(pEh + i1) = h1;
      *(short*)(pEl + i0) = lo0;
      *(short*)(pEl + i1) = lo1;
    }
  }
  __syncthreads();

  // ---- Phase L: logits via MFMA (wave 0), softmax in-register ----
  if (wv == 0) {
    f32x4 lacc = (f32x4){0.f, 0.f, 0.f, 0.f};
    const char* pEh = (const char*)u.e.Eh;
    const char* pEl = (const char*)u.e.El;
    const int rsw = (l15 & 7) << 4;
#pragma unroll
    for (int ks = 0; ks < 4; ++ks) {
      const int cbyte = ks * 64 + l4 * 16;
      const int o = l15 * 256 + (cbyte ^ rsw);
      s16x8 eh = *(const s16x8*)(pEh + o);
      s16x8 el = *(const s16x8*)(pEl + o);
      const size_t g = (size_t)l15 * 128 + ks * 32 + l4 * 8;
      s16x8 ch = *(const s16x8*)(cbh + g);
      s16x8 cl = *(const s16x8*)(cbl + g);
      lacc = __builtin_amdgcn_mfma_f32_16x16x32_bf16(eh, ch, lacc, 0, 0, 0);
      lacc = __builtin_amdgcn_mfma_f32_16x16x32_bf16(el, ch, lacc, 0, 0, 0);
      lacc = __builtin_amdgcn_mfma_f32_16x16x32_bf16(eh, cl, lacc, 0, 0, 0);
    }
    float* lg_out = out + O3 + ((size_t)bi * KK + j0) * NN;
    float* ag_out = out + O1 + ((size_t)bi * KK + j0) * NN;
#pragma unroll
    for (int r = 0; r < 4; ++r) {
      const int row = l4 * 4 + r;
      float lg = lacc[r] * 10.0f;
      float mx = lg;
#pragma unroll
      for (int m = 1; m < 16; m <<= 1) mx = fmaxf(mx, __shfl_xor(mx, m));
      float p = __expf(lg - mx);
      float s = p;
#pragma unroll
      for (int m = 1; m < 16; m <<= 1) s += __shfl_xor(s, m);
      float a = p / s;
      lg_out[row * 16 + l15] = lg;
      ag_out[row * 16 + l15] = a;
      sAlp[row * 32 + l15] = f2bf(a);
    }
  }
  __syncthreads();

  // ---- Phase M: m = alpha @ cb, one MFMA per 16-col group ----
  {
    // A frag (16x16x32): lane: row=l15, k=l4*8..+7 (k>=16 zero-padded)
    s16x8 af = *(const s16x8*)(sAlp + l15 * 32 + l4 * 8);
    float* mg = out + O0 + ((size_t)bi * KK + j0) * DD;
#pragma unroll
    for (int nt = 0; nt < 2; ++nt) {
      const int c = nb + nt * 16 + l15;
      s16x8 bf = *(const s16x8*)(cbT + (size_t)c * 32 + l4 * 8);
      f32x4 mac = (f32x4){0.f, 0.f, 0.f, 0.f};
      mac = __builtin_amdgcn_mfma_f32_16x16x32_bf16(af, bf, mac, 0, 0, 0);
#pragma unroll
      for (int r = 0; r < 4; ++r)
        mg[(l4 * 4 + r) * 128 + c] = mac[r];
    }
  }
}

extern "C" void kernel_launch(void* const* d_in, const int* in_sizes, int n_in,
                              void* d_out, int out_size, void* d_ws, size_t ws_size,
                              hipStream_t stream) {
  const float* z  = (const float*)d_in[0];   // (256,32,128)
  const float* W1 = (const float*)d_in[1];   // (256,256)
  const float* b1 = (const float*)d_in[2];   // (256,)
  const float* W2 = (const float*)d_in[3];   // (256,128)
  const float* b2 = (const float*)d_in[4];   // (128,)
  const float* cb = (const float*)d_in[5];   // (16,128)
  float* out = (float*)d_out;

  // ws: Hcat fp32 [8192][512] | zb | W1th | W1tl | Wh | Wl | cbh | cbl | cbT
  float* Hcat = (float*)d_ws;
  short* zb   = (short*)(Hcat + (size_t)8192 * 512);
  short* W1th = zb + (size_t)1048576;
  short* W1tl = W1th + (size_t)65536;
  short* Wh   = W1tl + (size_t)65536;
  short* Wl   = Wh + (size_t)32768;
  short* cbh  = Wl + (size_t)32768;
  short* cbl  = cbh + (size_t)2048;
  short* cbT  = cbl + (size_t)2048;

  prep_kernel<<<4096, 256, 0, stream>>>(z, W1, W2, cb, zb, W1th, W1tl, Wh, Wl,
                                        cbh, cbl, cbT);
  hproj_mfma<<<dim3(256, 4), 256, 0, stream>>>(zb, W1th, W1tl, Hcat);
  pair_kernel<<<BB * KK * 2, 256, 0, stream>>>(Hcat, b1, Wh, Wl, b2, cbh, cbl,
                                               cbT, out);
}

// Round 6
// 201.122 us; speedup vs baseline: 1.5126x; 1.5126x over previous
//
#include <hip/hip_runtime.h>
#include <hip/hip_bf16.h>
#include <math.h>

// Problem constants
#define BB 256
#define KK 32
#define DD 128
#define HH 256
#define NN 16
// d_out layout (fp32, concatenated in return order)
#define O0 ((size_t)0)
#define O1 ((size_t)33554432)
#define O2 ((size_t)37748736)
#define O3 ((size_t)71303168)

typedef float f32x4 __attribute__((ext_vector_type(4)));
typedef short s16x8 __attribute__((ext_vector_type(8)));

static __device__ __forceinline__ short f2bf(float x) {
  __hip_bfloat16 h = __float2bfloat16(x);
  return *reinterpret_cast<short*>(&h);
}
static __device__ __forceinline__ float bf2f(short s) {
  __hip_bfloat16 h;
  *reinterpret_cast<short*>(&h) = s;
  return __bfloat162float(h);
}
// pack 2 f32 -> 2 bf16 (RNE) in one instruction: lo16 = bf16(a), hi16 = bf16(b)
static __device__ __forceinline__ unsigned cvt_pk_bf16(float a, float b) {
  unsigned r;
  asm volatile("v_cvt_pk_bf16_f32 %0, %1, %2" : "=v"(r) : "v"(a), "v"(b));
  return r;
}

// exact-erf gelu via Abramowitz-Stegun 7.1.26 (|erf err| <= 1.5e-7)
static __device__ __forceinline__ float gelu_exact(float x) {
  float ax = fabsf(x) * 0.70710678118654752f;
  float t = __builtin_amdgcn_rcpf(fmaf(0.3275911f, ax, 1.0f));
  float p = fmaf(1.061405429f, t, -1.453152027f);
  p = fmaf(p, t, 1.421413741f);
  p = fmaf(p, t, -0.284496736f);
  p = fmaf(p, t, 0.254829592f);
  p *= t;
  float e = __expf(-ax * ax);
  float er = fmaf(-p, e, 1.0f);  // erf(|x|/sqrt2)
  er = copysignf(er, x);
  return 0.5f * x * (1.0f + er);
}

// ---------------------------------------------------------------------------
// Prep: z -> bf16; W1 -> transposed hi/lo bf16 [col 512][k 128];
//       W2 -> transposed hi/lo bf16 [col 128][k 256]; cb -> hi/lo [n][k];
//       cbT -> bf16 [c 128][n 32] (n 16..31 zero-padded, for Phase M MFMA).
// ---------------------------------------------------------------------------
__global__ __launch_bounds__(256) void prep_kernel(
    const float* __restrict__ z, const float* __restrict__ W1,
    const float* __restrict__ W2, const float* __restrict__ cb,
    short* __restrict__ zb, short* __restrict__ W1th, short* __restrict__ W1tl,
    short* __restrict__ Wh, short* __restrict__ Wl,
    short* __restrict__ cbh, short* __restrict__ cbl, short* __restrict__ cbT) {
  const int idx = blockIdx.x * 256 + threadIdx.x;  // 1,048,576 total
  zb[idx] = f2bf(z[idx]);
  if (idx < 512 * 128) {  // W1t
    int c = idx >> 7, k = idx & 127;
    float w = (c < 256) ? W1[(size_t)k * 256 + c]
                        : W1[(size_t)(128 + k) * 256 + (c - 256)];
    short h = f2bf(w);
    W1th[idx] = h;
    W1tl[idx] = f2bf(w - bf2f(h));
  }
  if (idx < 128 * 256) {  // W2t: [c][k]
    int c = idx >> 8, k = idx & 255;
    float w = W2[(size_t)k * 128 + c];
    short h = f2bf(w);
    Wh[idx] = h;
    Wl[idx] = f2bf(w - bf2f(h));
  }
  if (idx < 2048) {  // cb [n][k] splits
    float v = cb[idx];
    short h = f2bf(v);
    cbh[idx] = h;
    cbl[idx] = f2bf(v - bf2f(h));
  }
  if (idx < 128 * 32) {  // cbT [c][n], zero-padded n>=16
    int c = idx >> 5, n = idx & 31;
    cbT[idx] = (n < 16) ? f2bf(cb[(size_t)n * 128 + c]) : (short)0;
  }
}

// ---------------------------------------------------------------------------
// H projection via MFMA: Hcat[8192][512] = zb(8192x128) @ W1t^T (split-bf16).
// b1 is folded into the i-half (cols < 256).
// ---------------------------------------------------------------------------
__global__ __launch_bounds__(256) void hproj_mfma(
    const short* __restrict__ zb, const short* __restrict__ W1th,
    const short* __restrict__ W1tl, const float* __restrict__ b1,
    float* __restrict__ H) {
  const int tid = threadIdx.x;
  const int lane = tid & 63;
  const int wv = tid >> 6;
  const int l4 = lane >> 4, l15 = lane & 15;
  const int row0 = blockIdx.x * 32;
  const int col0 = blockIdx.y * 128 + wv * 32;

  f32x4 acc[2][2];
#pragma unroll
  for (int mt = 0; mt < 2; ++mt)
#pragma unroll
    for (int nt = 0; nt < 2; ++nt)
      acc[mt][nt] = (f32x4){0.f, 0.f, 0.f, 0.f};

#pragma unroll
  for (int ks = 0; ks < 4; ++ks) {
    const int kof = ks * 32 + l4 * 8;
    s16x8 a0 = *(const s16x8*)(zb + (size_t)(row0 + l15) * 128 + kof);
    s16x8 a1 = *(const s16x8*)(zb + (size_t)(row0 + 16 + l15) * 128 + kof);
    s16x8 bh0 = *(const s16x8*)(W1th + (size_t)(col0 + l15) * 128 + kof);
    s16x8 bh1 = *(const s16x8*)(W1th + (size_t)(col0 + 16 + l15) * 128 + kof);
    s16x8 bl0 = *(const s16x8*)(W1tl + (size_t)(col0 + l15) * 128 + kof);
    s16x8 bl1 = *(const s16x8*)(W1tl + (size_t)(col0 + 16 + l15) * 128 + kof);
    acc[0][0] = __builtin_amdgcn_mfma_f32_16x16x32_bf16(a0, bh0, acc[0][0], 0, 0, 0);
    acc[0][0] = __builtin_amdgcn_mfma_f32_16x16x32_bf16(a0, bl0, acc[0][0], 0, 0, 0);
    acc[0][1] = __builtin_amdgcn_mfma_f32_16x16x32_bf16(a0, bh1, acc[0][1], 0, 0, 0);
    acc[0][1] = __builtin_amdgcn_mfma_f32_16x16x32_bf16(a0, bl1, acc[0][1], 0, 0, 0);
    acc[1][0] = __builtin_amdgcn_mfma_f32_16x16x32_bf16(a1, bh0, acc[1][0], 0, 0, 0);
    acc[1][0] = __builtin_amdgcn_mfma_f32_16x16x32_bf16(a1, bl0, acc[1][0], 0, 0, 0);
    acc[1][1] = __builtin_amdgcn_mfma_f32_16x16x32_bf16(a1, bh1, acc[1][1], 0, 0, 0);
    acc[1][1] = __builtin_amdgcn_mfma_f32_16x16x32_bf16(a1, bl1, acc[1][1], 0, 0, 0);
  }

#pragma unroll
  for (int nt = 0; nt < 2; ++nt) {
    const int col = col0 + nt * 16 + l15;
    const float bias = (col0 < 256) ? b1[col] : 0.f;  // wave-uniform branch
#pragma unroll
    for (int mt = 0; mt < 2; ++mt)
#pragma unroll
      for (int r = 0; r < 4; ++r)
        H[(size_t)(row0 + mt * 16 + l4 * 4 + r) * 512 + col] =
            acc[mt][nt][r] + bias;
  }
}

// ---------------------------------------------------------------------------
// Kernel B: one block (4 waves) per (b,i); all 32 j's.
// ---------------------------------------------------------------------------
__global__ __launch_bounds__(256, 4) void pair_kernel(
    const float* __restrict__ Hcat, const short* __restrict__ Wh,
    const short* __restrict__ Wl, const float* __restrict__ b2,
    const short* __restrict__ cbh, const short* __restrict__ cbl,
    const short* __restrict__ cbT, float* __restrict__ out) {
  __shared__ short sAh[32 * 256];  // 16 KB gelu hi split, XOR-swizzled
  __shared__ union {
    short Al[32 * 256];  // 16 KB gelu lo split (dead after G)
    struct { short Eh[32 * 128]; short El[32 * 128]; } e;
  } u;
  __shared__ short sAlp[32 * 32];  // 2 KB alpha bf16, n zero-padded to 32

  const int tid = threadIdx.x;
  const int blk = blockIdx.x;  // = b*K + i
  const int b = blk >> 5;

  // zero-init alpha buffer (pad cols must be 0, not garbage/NaN)
  ((unsigned*)sAlp)[tid] = 0u;
  ((unsigned*)sAlp)[tid + 256] = 0u;

  // ---- Phase A: gelu + split-bf16 into swizzled LDS (b1 pre-folded) ----
  {
    const int k0 = (tid & 127) * 2;
    const int pb = (tid >> 7) * 16;
    const float2 hiv = *(const float2*)(Hcat + (size_t)blk * 512 + k0);
    const float hx = hiv.x;
    const float hy = hiv.y;
    const float* hjp = Hcat + ((size_t)b * KK + pb) * 512 + 256 + k0;
    unsigned* aH = (unsigned*)sAh;
    unsigned* aL = (unsigned*)u.Al;
    const int cw = tid & 127;
#pragma unroll 4
    for (int p = 0; p < 16; ++p) {
      const int row = pb + p;
      float2 hj = *(const float2*)(hjp + (size_t)p * 512);
      float g0 = gelu_exact(hx + hj.x);
      float g1 = gelu_exact(hy + hj.y);
      unsigned h01 = cvt_pk_bf16(g0, g1);
      float h0f = __uint_as_float(h01 << 16);
      float h1f = __uint_as_float(h01 & 0xFFFF0000u);
      unsigned l01 = cvt_pk_bf16(g0 - h0f, g1 - h1f);
      const int wi = row * 128 + ((cw ^ ((row & 7) << 2)));
      aH[wi] = h01;
      aL[wi] = l01;
    }
  }
  __syncthreads();

  // ---- Phase G: 32x128 GEMM, K=256, split-bf16 MFMA ----
  const int lane = tid & 63;
  const int wv = tid >> 6;  // wave owns cols nb..nb+31
  const int nb = wv * 32;
  const int l4 = lane >> 4;
  const int l15 = lane & 15;

  f32x4 acc[2][2];
#pragma unroll
  for (int mt = 0; mt < 2; ++mt)
#pragma unroll
    for (int nt = 0; nt < 2; ++nt)
      acc[mt][nt] = (f32x4){0.f, 0.f, 0.f, 0.f};

  const int sw = (l15 & 7) << 4;
  const char* pAh = (const char*)sAh;
  const char* pAl = (const char*)u.Al;
  const size_t gB0 = (size_t)(nb + l15) * 256 + l4 * 8;

#pragma unroll
  for (int ks = 0; ks < 8; ++ks) {
    const int cbyte = ks * 64 + l4 * 16;
    const int o0 = l15 * 512 + (cbyte ^ sw);
    const int o1 = (16 + l15) * 512 + (cbyte ^ sw);
    s16x8 ah0 = *(const s16x8*)(pAh + o0);
    s16x8 ah1 = *(const s16x8*)(pAh + o1);
    s16x8 al0 = *(const s16x8*)(pAl + o0);
    s16x8 al1 = *(const s16x8*)(pAl + o1);
    const size_t g0 = gB0 + ks * 32;
    const size_t g1 = g0 + 16 * 256;
    s16x8 bh0 = *(const s16x8*)(Wh + g0);
    s16x8 bh1 = *(const s16x8*)(Wh + g1);
    s16x8 bl0 = *(const s16x8*)(Wl + g0);
    s16x8 bl1 = *(const s16x8*)(Wl + g1);

    acc[0][0] = __builtin_amdgcn_mfma_f32_16x16x32_bf16(ah0, bh0, acc[0][0], 0, 0, 0);
    acc[0][0] = __builtin_amdgcn_mfma_f32_16x16x32_bf16(al0, bh0, acc[0][0], 0, 0, 0);
    acc[0][0] = __builtin_amdgcn_mfma_f32_16x16x32_bf16(ah0, bl0, acc[0][0], 0, 0, 0);
    acc[0][1] = __builtin_amdgcn_mfma_f32_16x16x32_bf16(ah0, bh1, acc[0][1], 0, 0, 0);
    acc[0][1] = __builtin_amdgcn_mfma_f32_16x16x32_bf16(al0, bh1, acc[0][1], 0, 0, 0);
    acc[0][1] = __builtin_amdgcn_mfma_f32_16x16x32_bf16(ah0, bl1, acc[0][1], 0, 0, 0);
    acc[1][0] = __builtin_amdgcn_mfma_f32_16x16x32_bf16(ah1, bh0, acc[1][0], 0, 0, 0);
    acc[1][0] = __builtin_amdgcn_mfma_f32_16x16x32_bf16(al1, bh0, acc[1][0], 0, 0, 0);
    acc[1][0] = __builtin_amdgcn_mfma_f32_16x16x32_bf16(ah1, bl0, acc[1][0], 0, 0, 0);
    acc[1][1] = __builtin_amdgcn_mfma_f32_16x16x32_bf16(ah1, bh1, acc[1][1], 0, 0, 0);
    acc[1][1] = __builtin_amdgcn_mfma_f32_16x16x32_bf16(al1, bh1, acc[1][1], 0, 0, 0);
    acc[1][1] = __builtin_amdgcn_mfma_f32_16x16x32_bf16(ah1, bl1, acc[1][1], 0, 0, 0);
  }

  __syncthreads();  // sAh/u.Al fully consumed; u.e may be written

  // ---- Phase E: +b2, fp32 e to global from regs, bf16 splits to LDS ----
  {
    const float b2v0 = b2[nb + l15];
    const float b2v1 = b2[nb + 16 + l15];
    float* eg = out + O2 + (size_t)blk * (KK * DD);
    char* pEh = (char*)u.e.Eh;
    char* pEl = (char*)u.e.El;
#pragma unroll
    for (int mt = 0; mt < 2; ++mt) {
#pragma unroll
      for (int r = 0; r < 4; ++r) {
        const int row = mt * 16 + l4 * 4 + r;
        const int rsw = (row & 7) << 4;
        const float e0 = acc[mt][0][r] + b2v0;
        const float e1 = acc[mt][1][r] + b2v1;
        eg[row * 128 + nb + l15] = e0;
        eg[row * 128 + nb + 16 + l15] = e1;
        unsigned hp = cvt_pk_bf16(e0, e1);
        float h0f = __uint_as_float(hp << 16);
        float h1f = __uint_as_float(hp & 0xFFFF0000u);
        unsigned lp = cvt_pk_bf16(e0 - h0f, e1 - h1f);
        const int i0 = row * 256 + (((nb + l15) * 2) ^ rsw);
        const int i1 = row * 256 + (((nb + 16 + l15) * 2) ^ rsw);
        *(short*)(pEh + i0) = (short)(hp & 0xFFFFu);
        *(short*)(pEh + i1) = (short)(hp >> 16);
        *(short*)(pEl + i0) = (short)(lp & 0xFFFFu);
        *(short*)(pEl + i1) = (short)(lp >> 16);
      }
    }
  }
  __syncthreads();

  // ---- Phase L: logits via MFMA (waves 0,1), softmax in-register ----
  if (wv < 2) {
    const int mrow = wv * 16;
    f32x4 lacc = (f32x4){0.f, 0.f, 0.f, 0.f};
    const char* pEh = (const char*)u.e.Eh;
    const char* pEl = (const char*)u.e.El;
    const int rowa = mrow + l15;
    const int rsw = (rowa & 7) << 4;
#pragma unroll
    for (int ks = 0; ks < 4; ++ks) {
      const int cbyte = ks * 64 + l4 * 16;
      const int o = rowa * 256 + (cbyte ^ rsw);
      s16x8 eh = *(const s16x8*)(pEh + o);
      s16x8 el = *(const s16x8*)(pEl + o);
      const size_t g = (size_t)l15 * 128 + ks * 32 + l4 * 8;
      s16x8 ch = *(const s16x8*)(cbh + g);
      s16x8 cl = *(const s16x8*)(cbl + g);
      lacc = __builtin_amdgcn_mfma_f32_16x16x32_bf16(eh, ch, lacc, 0, 0, 0);
      lacc = __builtin_amdgcn_mfma_f32_16x16x32_bf16(el, ch, lacc, 0, 0, 0);
      lacc = __builtin_amdgcn_mfma_f32_16x16x32_bf16(eh, cl, lacc, 0, 0, 0);
    }
    float* lg_out = out + O3 + (size_t)blk * (KK * NN);
    float* ag_out = out + O1 + (size_t)blk * (KK * NN);
#pragma unroll
    for (int r = 0; r < 4; ++r) {
      const int row = mrow + l4 * 4 + r;
      float lg = lacc[r] * 10.0f;
      float mx = lg;
#pragma unroll
      for (int m = 1; m < 16; m <<= 1) mx = fmaxf(mx, __shfl_xor(mx, m));
      float p = __expf(lg - mx);
      float s = p;
#pragma unroll
      for (int m = 1; m < 16; m <<= 1) s += __shfl_xor(s, m);
      float a = p / s;
      lg_out[row * 16 + l15] = lg;
      ag_out[row * 16 + l15] = a;
      sAlp[row * 32 + l15] = f2bf(a);
    }
  }
  __syncthreads();

  // ---- Phase M: m = alpha @ cb via MFMA (n zero-padded to 32) ----
  {
    float* mg = out + O0 + (size_t)blk * (KK * DD);
#pragma unroll
    for (int rg = 0; rg < 2; ++rg) {
      // A frag: row = rg*16 + l15, k(n) = l4*8..+7
      s16x8 af = *(const s16x8*)(sAlp + (rg * 16 + l15) * 32 + l4 * 8);
#pragma unroll
      for (int nt = 0; nt < 2; ++nt) {
        const int c = nb + nt * 16 + l15;
        s16x8 bf = *(const s16x8*)(cbT + (size_t)c * 32 + l4 * 8);
        f32x4 mac = (f32x4){0.f, 0.f, 0.f, 0.f};
        mac = __builtin_amdgcn_mfma_f32_16x16x32_bf16(af, bf, mac, 0, 0, 0);
#pragma unroll
        for (int r = 0; r < 4; ++r)
          mg[(rg * 16 + l4 * 4 + r) * 128 + c] = mac[r];
      }
    }
  }
}

extern "C" void kernel_launch(void* const* d_in, const int* in_sizes, int n_in,
                              void* d_out, int out_size, void* d_ws, size_t ws_size,
                              hipStream_t stream) {
  const float* z  = (const float*)d_in[0];   // (256,32,128)
  const float* W1 = (const float*)d_in[1];   // (256,256)
  const float* b1 = (const float*)d_in[2];   // (256,)
  const float* W2 = (const float*)d_in[3];   // (256,128)
  const float* b2 = (const float*)d_in[4];   // (128,)
  const float* cb = (const float*)d_in[5];   // (16,128)
  float* out = (float*)d_out;

  // ws: Hcat fp32 [8192][512] | zb | W1th | W1tl | Wh | Wl | cbh | cbl | cbT
  float* Hcat = (float*)d_ws;
  short* zb   = (short*)(Hcat + (size_t)8192 * 512);
  short* W1th = zb + (size_t)1048576;
  short* W1tl = W1th + (size_t)65536;
  short* Wh   = W1tl + (size_t)65536;
  short* Wl   = Wh + (size_t)32768;
  short* cbh  = Wl + (size_t)32768;
  short* cbl  = cbh + (size_t)2048;
  short* cbT  = cbl + (size_t)2048;

  prep_kernel<<<4096, 256, 0, stream>>>(z, W1, W2, cb, zb, W1th, W1tl, Wh, Wl,
                                        cbh, cbl, cbT);
  hproj_mfma<<<dim3(256, 4), 256, 0, stream>>>(zb, W1th, W1tl, b1, Hcat);
  pair_kernel<<<BB * KK, 256, 0, stream>>>(Hcat, Wh, Wl, b2, cbh, cbl, cbT, out);
}